// Round 1
// baseline (614.893 us; speedup 1.0000x reference)
//
#include <hip/hip_runtime.h>
#include <hip/hip_bf16.h>

#define B_   8
#define TQ_  8
#define TP_  447
#define TC_  1500
#define D_   1280
#define H_   20
#define DH_  64
#define DFF_ 5120
#define M_   64    // B_*TQ_ total rows

// ================= LayerNorm: row-major fp32 input -> transposed f32 [D_][M_]
__global__ __launch_bounds__(256) void ln_kernel(const float* __restrict__ X,
    const float* __restrict__ g, const float* __restrict__ be, float* __restrict__ outT)
{
  __shared__ float redA[4], redB[4];
  const int m = blockIdx.x;
  const int tid = threadIdx.x;
  float v[5];
#pragma unroll
  for (int t = 0; t < 5; ++t) v[t] = X[(size_t)m*D_ + tid + t*256];
  float s = v[0]+v[1]+v[2]+v[3]+v[4];
#pragma unroll
  for (int o = 32; o; o >>= 1) s += __shfl_down(s, o, 64);
  if ((tid & 63) == 0) redA[tid >> 6] = s;
  __syncthreads();
  const float mean = (redA[0]+redA[1]+redA[2]+redA[3]) * (1.0f/D_);
  float q = 0.f;
#pragma unroll
  for (int t = 0; t < 5; ++t) { const float d = v[t]-mean; q += d*d; }
#pragma unroll
  for (int o = 32; o; o >>= 1) q += __shfl_down(q, o, 64);
  if ((tid & 63) == 0) redB[tid >> 6] = q;
  __syncthreads();
  const float rstd = rsqrtf((redB[0]+redB[1]+redB[2]+redB[3]) * (1.0f/D_) + 1e-5f);
#pragma unroll
  for (int t = 0; t < 5; ++t) {
    const int c = tid + t*256;
    outT[(size_t)c*M_ + m] = (v[t]-mean)*rstd*g[c] + be[c];
  }
}

// ================= split-K GEMM: P[s][m][n] = sum_{k in chunk s} XT[k][m]*W[k][n]
__global__ __launch_bounds__(256) void gemm_splitk(
    const float* __restrict__ XT,
    const float* __restrict__ Wa, const float* __restrict__ Wb, const float* __restrict__ Wc,
    float* __restrict__ Pa, float* __restrict__ Pb, float* __restrict__ Pc,
    int N, int chunk)
{
  __shared__ float xs[64][64];
  const int z = blockIdx.z;
  const float* W = (z == 0 ? Wa : (z == 1 ? Wb : Wc));
  float* P = (z == 0 ? Pa : (z == 1 ? Pb : Pc));
  const int tid  = threadIdx.x;
  const int lane = tid & 63;
  const int wv   = tid >> 6;
  const int n    = blockIdx.x*128 + lane*2;
  const int k0   = blockIdx.y * chunk;
  float accL[16], accH[16];
#pragma unroll
  for (int r = 0; r < 16; ++r) { accL[r] = 0.f; accH[r] = 0.f; }

  for (int kb = 0; kb < chunk; kb += 64) {
    __syncthreads();
    {
      const float4* src = (const float4*)(XT + (size_t)(k0 + kb)*M_);
      float4* dst = (float4*)&xs[0][0];
#pragma unroll
      for (int i = 0; i < 4; ++i) dst[tid + i*256] = src[tid + i*256];
    }
    __syncthreads();
    const float* Wp = W + (size_t)(k0 + kb)*N + n;
    for (int kk = 0; kk < 64; ++kk) {
      const float2 wp = *(const float2*)(Wp + (size_t)kk*N);
      const float wl = wp.x;
      const float wh = wp.y;
      const float* xr = &xs[kk][wv*16];
#pragma unroll
      for (int r4 = 0; r4 < 4; ++r4) {
        const float4 xv = *(const float4*)(xr + r4*4);
        accL[r4*4+0] += xv.x*wl; accH[r4*4+0] += xv.x*wh;
        accL[r4*4+1] += xv.y*wl; accH[r4*4+1] += xv.y*wh;
        accL[r4*4+2] += xv.z*wl; accH[r4*4+2] += xv.z*wh;
        accL[r4*4+3] += xv.w*wl; accH[r4*4+3] += xv.w*wh;
      }
    }
  }
#pragma unroll
  for (int r = 0; r < 16; ++r) {
    const int m = wv*16 + r;
    float2 st; st.x = accL[r]; st.y = accH[r];
    *(float2*)(P + ((size_t)blockIdx.y*M_ + m)*N + n) = st;
  }
}

// ================= epilogue: sum split-K partials, +bias, gelu, +residual, multi-format out
__global__ __launch_bounds__(256) void epilogue_kernel(
    const float* __restrict__ P, int S, int N,
    const float* __restrict__ bias,
    const float* __restrict__ res,
    int gelu,
    float* __restrict__ outA, float* __restrict__ outT, float* __restrict__ outB)
{
  const int idx = blockIdx.x*256 + threadIdx.x;   // < M_*N
  const int m = idx / N;
  const int n = idx - m*N;
  float a = 0.f;
  for (int s = 0; s < S; ++s) a += P[((size_t)s*M_ + m)*N + n];
  if (bias) a += bias[n];
  if (gelu) a = 0.5f*a*(1.0f + erff(a*0.70710678118654752f));
  if (res) a += res[idx];
  if (outA) outA[idx] = a;
  if (outT) outT[(size_t)n*M_ + m] = a;
  if (outB) outB[idx] = a;
}

// ================= fused epilogue (sum partials + bias + residual) + LayerNorm
// one block per row m; writes row-major residual-out AND LN'd transposed [D_][M_]
__global__ __launch_bounds__(256) void epilogue_ln(
    const float* __restrict__ P, int S,
    const float* __restrict__ bias, const float* __restrict__ res,
    const float* __restrict__ g, const float* __restrict__ be,
    float* __restrict__ outRow, float* __restrict__ outT)
{
  __shared__ float redA[4], redB[4];
  const int m = blockIdx.x;
  const int tid = threadIdx.x;
  float v[5];
#pragma unroll
  for (int t = 0; t < 5; ++t) {
    const int c = tid + t*256;
    float a = 0.f;
    for (int s = 0; s < S; ++s) a += P[((size_t)s*M_ + m)*D_ + c];
    a += bias[c] + res[(size_t)m*D_ + c];
    outRow[(size_t)m*D_ + c] = a;
    v[t] = a;
  }
  float s = v[0]+v[1]+v[2]+v[3]+v[4];
#pragma unroll
  for (int o = 32; o; o >>= 1) s += __shfl_down(s, o, 64);
  if ((tid & 63) == 0) redA[tid >> 6] = s;
  __syncthreads();
  const float mean = (redA[0]+redA[1]+redA[2]+redA[3]) * (1.0f/D_);
  float q = 0.f;
#pragma unroll
  for (int t = 0; t < 5; ++t) { const float d = v[t]-mean; q += d*d; }
#pragma unroll
  for (int o = 32; o; o >>= 1) q += __shfl_down(q, o, 64);
  if ((tid & 63) == 0) redB[tid >> 6] = q;
  __syncthreads();
  const float rstd = rsqrtf((redB[0]+redB[1]+redB[2]+redB[3]) * (1.0f/D_) + 1e-5f);
#pragma unroll
  for (int t = 0; t < 5; ++t) {
    const int c = tid + t*256;
    outT[(size_t)c*M_ + m] = (v[t]-mean)*rstd*g[c] + be[c];
  }
}

// ================= z-batched QKV epilogue: sum 10 partials, per-z bias/outputs
__global__ __launch_bounds__(256) void epilogue_qkv(
    const float* __restrict__ Pq, const float* __restrict__ Pk, const float* __restrict__ Pv,
    const float* __restrict__ bq, const float* __restrict__ bv,
    float* __restrict__ qbuf, float* __restrict__ k1f, float* __restrict__ v1f,
    float* __restrict__ out_k1, float* __restrict__ out_v1)
{
  const int z = blockIdx.z;
  const int idx = blockIdx.x*256 + threadIdx.x;   // < M_*D_
  const float* P = (z == 0 ? Pq : (z == 1 ? Pk : Pv));
  float a = 0.f;
#pragma unroll
  for (int s = 0; s < 10; ++s) a += P[(size_t)s*M_*D_ + idx];
  const int n = idx % D_;
  if (z == 0)      { a += bq[n]; qbuf[idx] = a; }
  else if (z == 1) { k1f[idx] = a; out_k1[idx] = a; }
  else             { a += bv[n]; v1f[idx] = a; out_v1[idx] = a; }
}

// ================= fused attention split: scores + softmax (LDS) + PV partial
// grid (SP, H_, B_), block 256. chunk <= 94.
// K tile is cooperatively staged into LDS (coalesced float4) before the score
// phase — the old thread-per-row direct-global pattern hit 64 distinct cache
// lines per wave load (row stride 5120B). Phase 1 uses 2 threads per key row.
// kr[] (26KB) is aliased as the phase-3 reduction buffer (8KB) -> 33KB LDS,
// 4 blocks/CU at __launch_bounds__(256,4).
#define SCS 10
__global__ __launch_bounds__(256, 4) void attn_fused(
    const float* __restrict__ Q,
    const float* __restrict__ Kc, const float* __restrict__ Kn,
    const float* __restrict__ Vc, const float* __restrict__ Vn,
    const float* __restrict__ mask,
    float* __restrict__ Opart, float* __restrict__ ML,
    int TK, int TPp, int chunk)
{
  __shared__ float sc[128*SCS];     // scores then exp-weights, [jl][SCS]
  __shared__ float qs[8*64];        // q rows for this (b,*,h)
  __shared__ float kr[96*68];       // K tile [row][68] (phase 0/1) == red (phase 3)
  const int tid = threadIdx.x;
  const int sp = blockIdx.x, h = blockIdx.y, b = blockIdx.z;
  const int SP = gridDim.x;
  const int j0 = sp * chunk;
  const int cnt = min(chunk, TK - j0);
  const int bh = b*H_ + h;

  // stage q: 512 floats (coalesced, lane=d)
  {
    const int i = tid >> 6, d = tid & 63;
    qs[tid]       = Q[((size_t)(b*TQ_ + i    ))*D_ + h*DH_ + d];
    qs[tid + 256] = Q[((size_t)(b*TQ_ + i + 4))*D_ + h*DH_ + d];
  }
  // stage K tile: cnt rows x 64 dims, coalesced float4 (16 lanes per row)
  for (int u = tid; u < cnt*16; u += 256) {
    const int r = u >> 4, c = u & 15;
    const int j = j0 + r;
    const float* kg = (j < TPp)
      ? Kc + ((size_t)b*TPp + j)*D_ + h*DH_
      : Kn + ((size_t)(b*TQ_ + (j - TPp)))*D_ + h*DH_;
    *(float4*)&kr[r*68 + c*4] = *(const float4*)(kg + c*4);
  }
  __syncthreads();

  // ---- phase 1: scores; 2 threads per key row (halves combined via shfl_xor) ----
  {
    const int jl = tid >> 1, hf = tid & 1;
    if (jl < cnt) {
      const float* krow = &kr[jl*68 + hf*32];
      float acc[8] = {0.f,0.f,0.f,0.f,0.f,0.f,0.f,0.f};
#pragma unroll
      for (int dc = 0; dc < 8; ++dc) {
        const float4 kf = *(const float4*)(krow + dc*4);
#pragma unroll
        for (int i = 0; i < 8; ++i) {
          const float4 qv = *(const float4*)&qs[i*64 + hf*32 + dc*4];
          acc[i] += qv.x*kf.x + qv.y*kf.y + qv.z*kf.z + qv.w*kf.w;
        }
      }
#pragma unroll
      for (int i = 0; i < 8; ++i) acc[i] += __shfl_xor(acc[i], 1, 64);
      if (!hf) {
        const int j = j0 + jl;
#pragma unroll
        for (int i = 0; i < 8; ++i) {
          float vv = acc[i]*0.125f;       // (dh^-0.25)^2 on the q.k product
          if (mask) vv += mask[(size_t)i*TK + j];
          sc[jl*SCS + i] = vv;
        }
      }
    }
  }
  __syncthreads();

  // ---- phase 2: per-split softmax, exp in place; 8 row-groups x 32 lanes ----
  {
    const int g = tid >> 5, l = tid & 31;
    float mx = -3.0e38f;
    for (int jl = l; jl < cnt; jl += 32) mx = fmaxf(mx, sc[jl*SCS + g]);
#pragma unroll
    for (int o = 16; o; o >>= 1) mx = fmaxf(mx, __shfl_down(mx, o, 32));
    mx = __shfl(mx, 0, 32);
    float sum = 0.f;
    for (int jl = l; jl < cnt; jl += 32) {
      const float e = __expf(sc[jl*SCS + g] - mx);
      sc[jl*SCS + g] = e;
      sum += e;
    }
#pragma unroll
    for (int o = 16; o; o >>= 1) sum += __shfl_down(sum, o, 32);
    if (l == 0) {
      ML[((size_t)bh*SP + sp)*16 + g]     = mx;
      ML[((size_t)bh*SP + sp)*16 + 8 + g] = sum;
    }
  }
  __syncthreads();

  // ---- phase 3: PV. Waves interleave over j (V read ONCE per block, 256B/instr);
  //      lane = d; all 8 q-rows accumulated per lane; LDS-broadcast weights ----
  {
    const int wv = tid >> 6;
    const int d  = tid & 63;
    float acc[8] = {0.f,0.f,0.f,0.f,0.f,0.f,0.f,0.f};
#pragma unroll 2
    for (int jl = wv; jl < cnt; jl += 4) {
      const int j = j0 + jl;
      const float vv = (j < TPp)
        ? Vc[((size_t)b*TPp + j)*D_ + h*DH_ + d]
        : Vn[((size_t)(b*TQ_ + (j - TPp)))*D_ + h*DH_ + d];
      const float2 p0 = *(const float2*)&sc[jl*SCS + 0];   // broadcast, conflict-free
      const float2 p1 = *(const float2*)&sc[jl*SCS + 2];
      const float2 p2 = *(const float2*)&sc[jl*SCS + 4];
      const float2 p3 = *(const float2*)&sc[jl*SCS + 6];
      acc[0] += p0.x*vv; acc[1] += p0.y*vv;
      acc[2] += p1.x*vv; acc[3] += p1.y*vv;
      acc[4] += p2.x*vv; acc[5] += p2.y*vv;
      acc[6] += p3.x*vv; acc[7] += p3.y*vv;
    }
#pragma unroll
    for (int i = 0; i < 8; ++i) kr[(wv*8 + i)*64 + d] = acc[i];
  }
  __syncthreads();
  {
#pragma unroll
    for (int t = 0; t < 2; ++t) {
      const int o = tid + t*256;        // < 512
      const int i = o >> 6, d = o & 63;
      const float r = kr[(0*8 + i)*64 + d] + kr[(1*8 + i)*64 + d]
                    + kr[(2*8 + i)*64 + d] + kr[(3*8 + i)*64 + d];
      Opart[(((size_t)bh*SP + sp)*8 + i)*64 + d] = r;
    }
  }
}

// ================= merge PV partials with split-softmax weights; outT f32 [D_][M_]
__global__ __launch_bounds__(256) void attn_pv_combine(
    const float* __restrict__ Opart, const float* __restrict__ ML,
    float* __restrict__ outT, int SP)
{
  const int tid = threadIdx.x;
  const int h = blockIdx.x, b = blockIdx.y;
  const int bh = b*H_ + h;
  const int wv = tid >> 6, d = tid & 63;
  const int i0 = wv*2, i1 = i0 + 1;
  float M0 = -3.0e38f, M1 = -3.0e38f;
  for (int s = 0; s < SP; ++s) {
    M0 = fmaxf(M0, ML[((size_t)bh*SP + s)*16 + i0]);
    M1 = fmaxf(M1, ML[((size_t)bh*SP + s)*16 + i1]);
  }
  float L0 = 0.f, L1 = 0.f, o0 = 0.f, o1 = 0.f;
  for (int s = 0; s < SP; ++s) {
    const float w0 = __expf(ML[((size_t)bh*SP + s)*16 + i0] - M0);
    const float w1 = __expf(ML[((size_t)bh*SP + s)*16 + i1] - M1);
    L0 += w0 * ML[((size_t)bh*SP + s)*16 + 8 + i0];
    L1 += w1 * ML[((size_t)bh*SP + s)*16 + 8 + i1];
    o0 += w0 * Opart[(((size_t)bh*SP + s)*8 + i0)*64 + d];
    o1 += w1 * Opart[(((size_t)bh*SP + s)*8 + i1)*64 + d];
  }
  outT[((size_t)(h*DH_ + d))*M_ + b*TQ_ + i0] = o0 / L0;
  outT[((size_t)(h*DH_ + d))*M_ + b*TQ_ + i1] = o1 / L1;
}

extern "C" void kernel_launch(void* const* d_in, const int* in_sizes, int n_in,
                              void* d_out, int out_size, void* d_ws, size_t ws_size,
                              hipStream_t stream)
{
  (void)in_sizes; (void)n_in; (void)out_size; (void)ws_size;
  const float* x    = (const float*)d_in[0];
  const float* skc  = (const float*)d_in[1];
  const float* svc  = (const float*)d_in[2];
  const float* ck   = (const float*)d_in[3];
  const float* cv   = (const float*)d_in[4];
  const float* msk  = (const float*)d_in[5];
  const float* wq   = (const float*)d_in[6];
  const float* bq   = (const float*)d_in[7];
  const float* wk   = (const float*)d_in[8];
  const float* wvv  = (const float*)d_in[9];
  const float* bv   = (const float*)d_in[10];
  const float* wo   = (const float*)d_in[11];
  const float* bo   = (const float*)d_in[12];
  const float* cwq  = (const float*)d_in[13];
  const float* cbq  = (const float*)d_in[14];
  const float* cwo  = (const float*)d_in[15];
  const float* cbo  = (const float*)d_in[16];
  const float* ln1w = (const float*)d_in[17];
  const float* ln1b = (const float*)d_in[18];
  const float* ln2w = (const float*)d_in[19];
  const float* ln2b = (const float*)d_in[20];
  const float* ln3w = (const float*)d_in[21];
  const float* ln3b = (const float*)d_in[22];
  const float* w1   = (const float*)d_in[23];
  const float* b1   = (const float*)d_in[24];
  const float* w2   = (const float*)d_in[25];
  const float* b2   = (const float*)d_in[26];
  // d_in[27] = offset (int) — fixed at TP_ here.

  float* out_x  = (float*)d_out;
  float* out_k1 = out_x + 81920;
  float* out_v1 = out_x + 163840;

  float* ws = (float*)d_ws;
  float* xlT  = ws + 0;               // [1280][64], reused 3x
  float* qbuf = ws + 81920;           // q / qc row-major [64][1280]
  float* k1f  = ws + 163840;
  float* v1f  = ws + 245760;
  float* x2   = ws + 327680;
  float* x3   = ws + 409600;
  float* attT = ws + 491520;          // attn out transposed, reused 2x
  float* hT   = ws + 573440;          // [5120][64]
  float* Pg   = ws + 901120;          // split-K partials / attention Opart
  float* Pq   = Pg;
  float* Pk   = Pg + 819200;
  float* Pv   = Pg + 1638400;
  float* MLS  = ws + 4177920;         // 160*8*16
  float* MLC  = ws + 4218880;         // 160*16*16

  const dim3 blk(256);

  // --- self-attention ---
  ln_kernel<<<dim3(64), blk, 0, stream>>>(x, ln1w, ln1b, xlT);
  gemm_splitk<<<dim3(10,10,3), blk, 0, stream>>>(xlT, wq, wk, wvv, Pq, Pk, Pv, 1280, 128);
  epilogue_qkv<<<dim3(320,1,3), blk, 0, stream>>>(Pq, Pk, Pv, bq, bv, qbuf, k1f, v1f, out_k1, out_v1);
  // SP=8, chunk=57 (8*57=456 >= 455)
  attn_fused<<<dim3(8,20,8), blk, 0, stream>>>(qbuf, skc, k1f, svc, v1f, msk, Pg, MLS, 455, 447, 57);
  attn_pv_combine<<<dim3(20,8), blk, 0, stream>>>(Pg, MLS, attT, 8);
  gemm_splitk<<<dim3(10,10,1), blk, 0, stream>>>(attT, wo, wo, wo, Pq, Pq, Pq, 1280, 128);
  epilogue_ln<<<dim3(64), blk, 0, stream>>>(Pq, 10, bo, x, ln2w, ln2b, x2, xlT);

  // --- cross-attention ---
  gemm_splitk<<<dim3(10,10,1), blk, 0, stream>>>(xlT, cwq, cwq, cwq, Pq, Pq, Pq, 1280, 128);
  epilogue_kernel<<<dim3(320), blk, 0, stream>>>(Pq, 10, 1280, cbq, nullptr, 0, qbuf, nullptr, nullptr);
  // SP=16, chunk=94 (16*94=1504 >= 1500)
  attn_fused<<<dim3(16,20,8), blk, 0, stream>>>(qbuf, ck, nullptr, cv, nullptr, nullptr, Pg, MLC, 1500, 1500, 94);
  attn_pv_combine<<<dim3(20,8), blk, 0, stream>>>(Pg, MLC, attT, 16);
  gemm_splitk<<<dim3(10,10,1), blk, 0, stream>>>(attT, cwo, cwo, cwo, Pq, Pq, Pq, 1280, 128);
  epilogue_ln<<<dim3(64), blk, 0, stream>>>(Pq, 10, cbo, x2, ln3w, ln3b, x3, xlT);

  // --- MLP ---
  gemm_splitk<<<dim3(40,10,1), blk, 0, stream>>>(xlT, w1, w1, w1, Pg, Pg, Pg, 5120, 128);
  epilogue_kernel<<<dim3(1280), blk, 0, stream>>>(Pg, 10, 5120, b1, nullptr, 1, nullptr, hT, nullptr);
  gemm_splitk<<<dim3(10,40,1), blk, 0, stream>>>(hT, w2, w2, w2, Pg, Pg, Pg, 1280, 128);
  epilogue_kernel<<<dim3(320), blk, 0, stream>>>(Pg, 40, 1280, b2, x3, 0, nullptr, nullptr, out_x);
}

// Round 3
// 594.096 us; speedup vs baseline: 1.0350x; 1.0350x over previous
//
#include <hip/hip_runtime.h>
#include <hip/hip_bf16.h>

#define B_   8
#define TQ_  8
#define TP_  447
#define TC_  1500
#define D_   1280
#define H_   20
#define DH_  64
#define DFF_ 5120
#define M_   64    // B_*TQ_ total rows

// ================= LayerNorm: row-major fp32 input -> transposed f32 [D_][M_]
__global__ __launch_bounds__(256) void ln_kernel(const float* __restrict__ X,
    const float* __restrict__ g, const float* __restrict__ be, float* __restrict__ outT)
{
  __shared__ float redA[4], redB[4];
  const int m = blockIdx.x;
  const int tid = threadIdx.x;
  float v[5];
#pragma unroll
  for (int t = 0; t < 5; ++t) v[t] = X[(size_t)m*D_ + tid + t*256];
  float s = v[0]+v[1]+v[2]+v[3]+v[4];
#pragma unroll
  for (int o = 32; o; o >>= 1) s += __shfl_down(s, o, 64);
  if ((tid & 63) == 0) redA[tid >> 6] = s;
  __syncthreads();
  const float mean = (redA[0]+redA[1]+redA[2]+redA[3]) * (1.0f/D_);
  float q = 0.f;
#pragma unroll
  for (int t = 0; t < 5; ++t) { const float d = v[t]-mean; q += d*d; }
#pragma unroll
  for (int o = 32; o; o >>= 1) q += __shfl_down(q, o, 64);
  if ((tid & 63) == 0) redB[tid >> 6] = q;
  __syncthreads();
  const float rstd = rsqrtf((redB[0]+redB[1]+redB[2]+redB[3]) * (1.0f/D_) + 1e-5f);
#pragma unroll
  for (int t = 0; t < 5; ++t) {
    const int c = tid + t*256;
    outT[(size_t)c*M_ + m] = (v[t]-mean)*rstd*g[c] + be[c];
  }
}

// ================= split-K GEMM: P[s][m][n] = sum_{k in chunk s} XT[k][m]*W[k][n]
__global__ __launch_bounds__(256) void gemm_splitk(
    const float* __restrict__ XT,
    const float* __restrict__ Wa, const float* __restrict__ Wb, const float* __restrict__ Wc,
    float* __restrict__ Pa, float* __restrict__ Pb, float* __restrict__ Pc,
    int N, int chunk)
{
  __shared__ float xs[64][64];
  const int z = blockIdx.z;
  const float* W = (z == 0 ? Wa : (z == 1 ? Wb : Wc));
  float* P = (z == 0 ? Pa : (z == 1 ? Pb : Pc));
  const int tid  = threadIdx.x;
  const int lane = tid & 63;
  const int wv   = tid >> 6;
  const int n    = blockIdx.x*128 + lane*2;
  const int k0   = blockIdx.y * chunk;
  float accL[16], accH[16];
#pragma unroll
  for (int r = 0; r < 16; ++r) { accL[r] = 0.f; accH[r] = 0.f; }

  for (int kb = 0; kb < chunk; kb += 64) {
    __syncthreads();
    {
      const float4* src = (const float4*)(XT + (size_t)(k0 + kb)*M_);
      float4* dst = (float4*)&xs[0][0];
#pragma unroll
      for (int i = 0; i < 4; ++i) dst[tid + i*256] = src[tid + i*256];
    }
    __syncthreads();
    const float* Wp = W + (size_t)(k0 + kb)*N + n;
    for (int kk = 0; kk < 64; ++kk) {
      const float2 wp = *(const float2*)(Wp + (size_t)kk*N);
      const float wl = wp.x;
      const float wh = wp.y;
      const float* xr = &xs[kk][wv*16];
#pragma unroll
      for (int r4 = 0; r4 < 4; ++r4) {
        const float4 xv = *(const float4*)(xr + r4*4);
        accL[r4*4+0] += xv.x*wl; accH[r4*4+0] += xv.x*wh;
        accL[r4*4+1] += xv.y*wl; accH[r4*4+1] += xv.y*wh;
        accL[r4*4+2] += xv.z*wl; accH[r4*4+2] += xv.z*wh;
        accL[r4*4+3] += xv.w*wl; accH[r4*4+3] += xv.w*wh;
      }
    }
  }
#pragma unroll
  for (int r = 0; r < 16; ++r) {
    const int m = wv*16 + r;
    float2 st; st.x = accL[r]; st.y = accH[r];
    *(float2*)(P + ((size_t)blockIdx.y*M_ + m)*N + n) = st;
  }
}

// ================= epilogue: sum split-K partials, +bias, gelu, +residual, multi-format out
__global__ __launch_bounds__(256) void epilogue_kernel(
    const float* __restrict__ P, int S, int N,
    const float* __restrict__ bias,
    const float* __restrict__ res,
    int gelu,
    float* __restrict__ outA, float* __restrict__ outT, float* __restrict__ outB)
{
  const int idx = blockIdx.x*256 + threadIdx.x;   // < M_*N
  const int m = idx / N;
  const int n = idx - m*N;
  float a = 0.f;
  for (int s = 0; s < S; ++s) a += P[((size_t)s*M_ + m)*N + n];
  if (bias) a += bias[n];
  if (gelu) a = 0.5f*a*(1.0f + erff(a*0.70710678118654752f));
  if (res) a += res[idx];
  if (outA) outA[idx] = a;
  if (outT) outT[(size_t)n*M_ + m] = a;
  if (outB) outB[idx] = a;
}

// ================= fused epilogue (sum partials + bias + residual) + LayerNorm
__global__ __launch_bounds__(256) void epilogue_ln(
    const float* __restrict__ P, int S,
    const float* __restrict__ bias, const float* __restrict__ res,
    const float* __restrict__ g, const float* __restrict__ be,
    float* __restrict__ outRow, float* __restrict__ outT)
{
  __shared__ float redA[4], redB[4];
  const int m = blockIdx.x;
  const int tid = threadIdx.x;
  float v[5];
#pragma unroll
  for (int t = 0; t < 5; ++t) {
    const int c = tid + t*256;
    float a = 0.f;
    for (int s = 0; s < S; ++s) a += P[((size_t)s*M_ + m)*D_ + c];
    a += bias[c] + res[(size_t)m*D_ + c];
    outRow[(size_t)m*D_ + c] = a;
    v[t] = a;
  }
  float s = v[0]+v[1]+v[2]+v[3]+v[4];
#pragma unroll
  for (int o = 32; o; o >>= 1) s += __shfl_down(s, o, 64);
  if ((tid & 63) == 0) redA[tid >> 6] = s;
  __syncthreads();
  const float mean = (redA[0]+redA[1]+redA[2]+redA[3]) * (1.0f/D_);
  float q = 0.f;
#pragma unroll
  for (int t = 0; t < 5; ++t) { const float d = v[t]-mean; q += d*d; }
#pragma unroll
  for (int o = 32; o; o >>= 1) q += __shfl_down(q, o, 64);
  if ((tid & 63) == 0) redB[tid >> 6] = q;
  __syncthreads();
  const float rstd = rsqrtf((redB[0]+redB[1]+redB[2]+redB[3]) * (1.0f/D_) + 1e-5f);
#pragma unroll
  for (int t = 0; t < 5; ++t) {
    const int c = tid + t*256;
    outT[(size_t)c*M_ + m] = (v[t]-mean)*rstd*g[c] + be[c];
  }
}

// ================= z-batched QKV epilogue: sum 10 partials, per-z bias/outputs
__global__ __launch_bounds__(256) void epilogue_qkv(
    const float* __restrict__ Pq, const float* __restrict__ Pk, const float* __restrict__ Pv,
    const float* __restrict__ bq, const float* __restrict__ bv,
    float* __restrict__ qbuf, float* __restrict__ k1f, float* __restrict__ v1f,
    float* __restrict__ out_k1, float* __restrict__ out_v1)
{
  const int z = blockIdx.z;
  const int idx = blockIdx.x*256 + threadIdx.x;   // < M_*D_
  const float* P = (z == 0 ? Pq : (z == 1 ? Pk : Pv));
  float a = 0.f;
#pragma unroll
  for (int s = 0; s < 10; ++s) a += P[(size_t)s*M_*D_ + idx];
  const int n = idx % D_;
  if (z == 0)      { a += bq[n]; qbuf[idx] = a; }
  else if (z == 1) { k1f[idx] = a; out_k1[idx] = a; }
  else             { a += bv[n]; v1f[idx] = a; out_v1[idx] = a; }
}

// ================= fused attention split: scores + softmax (LDS) + PV partial
// grid (SP, H_, B_), block 256. chunk <= 64.
// LDS cut to ~22KB (chunk<=64) -> 7 blocks/CU (was 33KB -> 4); the R1 counters
// showed Occupancy 35% / VALUBusy 25% => latency-bound, need more resident waves.
// Phase 1: 4 threads per key row (16 dims each), shfl_xor combine -> 100% util.
#define SCS 10
__global__ __launch_bounds__(256, 7) void attn_fused(
    const float* __restrict__ Q,
    const float* __restrict__ Kc, const float* __restrict__ Kn,
    const float* __restrict__ Vc, const float* __restrict__ Vn,
    const float* __restrict__ mask,
    float* __restrict__ Opart, float* __restrict__ ML,
    int TK, int TPp, int chunk)
{
  __shared__ float sc[64*SCS];      // scores then exp-weights, [jl][SCS]  (2.5KB)
  __shared__ float qs[8*64];        // q rows for this (b,*,h)             (2KB)
  __shared__ float kr[64*68];       // K tile [row][68] (phase 0/1) == red (phase 3) (17KB)
  const int tid = threadIdx.x;
  const int sp = blockIdx.x, h = blockIdx.y, b = blockIdx.z;
  const int SP = gridDim.x;
  const int j0 = sp * chunk;
  const int cnt = min(chunk, TK - j0);
  const int bh = b*H_ + h;

  // stage q: 512 floats (coalesced, lane=d)
  {
    const int i = tid >> 6, d = tid & 63;
    qs[tid]       = Q[((size_t)(b*TQ_ + i    ))*D_ + h*DH_ + d];
    qs[tid + 256] = Q[((size_t)(b*TQ_ + i + 4))*D_ + h*DH_ + d];
  }
  // stage K tile: cnt rows x 64 dims, coalesced float4 (16 lanes per row)
  for (int u = tid; u < cnt*16; u += 256) {
    const int r = u >> 4, c = u & 15;
    const int j = j0 + r;
    const float* kg = (j < TPp)
      ? Kc + ((size_t)b*TPp + j)*D_ + h*DH_
      : Kn + ((size_t)(b*TQ_ + (j - TPp)))*D_ + h*DH_;
    *(float4*)&kr[r*68 + c*4] = *(const float4*)(kg + c*4);
  }
  __syncthreads();

  // ---- phase 1: scores; 4 threads per key row (16 dims each), shfl_xor combine ----
  {
    const int jl = tid >> 2, qt = tid & 3;
    if (jl < cnt) {
      const float* krow = &kr[jl*68 + qt*16];
      const float4 k0 = *(const float4*)(krow);
      const float4 k1 = *(const float4*)(krow + 4);
      const float4 k2 = *(const float4*)(krow + 8);
      const float4 k3 = *(const float4*)(krow + 12);
      float acc[8];
#pragma unroll
      for (int i = 0; i < 8; ++i) {
        const float* qp = &qs[i*64 + qt*16];
        const float4 q0 = *(const float4*)(qp);
        const float4 q1 = *(const float4*)(qp + 4);
        const float4 q2 = *(const float4*)(qp + 8);
        const float4 q3 = *(const float4*)(qp + 12);
        acc[i] = q0.x*k0.x + q0.y*k0.y + q0.z*k0.z + q0.w*k0.w
               + q1.x*k1.x + q1.y*k1.y + q1.z*k1.z + q1.w*k1.w
               + q2.x*k2.x + q2.y*k2.y + q2.z*k2.z + q2.w*k2.w
               + q3.x*k3.x + q3.y*k3.y + q3.z*k3.z + q3.w*k3.w;
      }
#pragma unroll
      for (int i = 0; i < 8; ++i) {
        acc[i] += __shfl_xor(acc[i], 1, 64);
        acc[i] += __shfl_xor(acc[i], 2, 64);
      }
      if (qt == 0) {
        const int j = j0 + jl;
#pragma unroll
        for (int i = 0; i < 8; ++i) {
          float vv = acc[i]*0.125f;       // (dh^-0.25)^2 on the q.k product
          if (mask) vv += mask[(size_t)i*TK + j];
          sc[jl*SCS + i] = vv;
        }
      }
    }
  }
  __syncthreads();

  // ---- phase 2: per-split softmax, exp in place; 8 row-groups x 32 lanes ----
  {
    const int g = tid >> 5, l = tid & 31;
    float mx = -3.0e38f;
    for (int jl = l; jl < cnt; jl += 32) mx = fmaxf(mx, sc[jl*SCS + g]);
#pragma unroll
    for (int o = 16; o; o >>= 1) mx = fmaxf(mx, __shfl_down(mx, o, 32));
    mx = __shfl(mx, 0, 32);
    float sum = 0.f;
    for (int jl = l; jl < cnt; jl += 32) {
      const float e = __expf(sc[jl*SCS + g] - mx);
      sc[jl*SCS + g] = e;
      sum += e;
    }
#pragma unroll
    for (int o = 16; o; o >>= 1) sum += __shfl_down(sum, o, 32);
    if (l == 0) {
      ML[((size_t)bh*SP + sp)*16 + g]     = mx;
      ML[((size_t)bh*SP + sp)*16 + 8 + g] = sum;
    }
  }
  __syncthreads();

  // ---- phase 3: PV. Waves interleave over j (V read ONCE per block, 256B/instr);
  //      lane = d; all 8 q-rows accumulated per lane; LDS-broadcast weights ----
  {
    const int wv = tid >> 6;
    const int d  = tid & 63;
    float acc[8] = {0.f,0.f,0.f,0.f,0.f,0.f,0.f,0.f};
#pragma unroll 4
    for (int jl = wv; jl < cnt; jl += 4) {
      const int j = j0 + jl;
      const float vv = (j < TPp)
        ? Vc[((size_t)b*TPp + j)*D_ + h*DH_ + d]
        : Vn[((size_t)(b*TQ_ + (j - TPp)))*D_ + h*DH_ + d];
      const float2 p0 = *(const float2*)&sc[jl*SCS + 0];   // broadcast, conflict-free
      const float2 p1 = *(const float2*)&sc[jl*SCS + 2];
      const float2 p2 = *(const float2*)&sc[jl*SCS + 4];
      const float2 p3 = *(const float2*)&sc[jl*SCS + 6];
      acc[0] += p0.x*vv; acc[1] += p0.y*vv;
      acc[2] += p1.x*vv; acc[3] += p1.y*vv;
      acc[4] += p2.x*vv; acc[5] += p2.y*vv;
      acc[6] += p3.x*vv; acc[7] += p3.y*vv;
    }
#pragma unroll
    for (int i = 0; i < 8; ++i) kr[(wv*8 + i)*64 + d] = acc[i];
  }
  __syncthreads();
  {
#pragma unroll
    for (int t = 0; t < 2; ++t) {
      const int o = tid + t*256;        // < 512
      const int i = o >> 6, d = o & 63;
      const float r = kr[(0*8 + i)*64 + d] + kr[(1*8 + i)*64 + d]
                    + kr[(2*8 + i)*64 + d] + kr[(3*8 + i)*64 + d];
      Opart[(((size_t)bh*SP + sp)*8 + i)*64 + d] = r;
    }
  }
}

// ================= merge PV partials with split-softmax weights; outT f32 [D_][M_]
__global__ __launch_bounds__(256) void attn_pv_combine(
    const float* __restrict__ Opart, const float* __restrict__ ML,
    float* __restrict__ outT, int SP)
{
  const int tid = threadIdx.x;
  const int h = blockIdx.x, b = blockIdx.y;
  const int bh = b*H_ + h;
  const int wv = tid >> 6, d = tid & 63;
  const int i0 = wv*2, i1 = i0 + 1;
  float M0 = -3.0e38f, M1 = -3.0e38f;
  for (int s = 0; s < SP; ++s) {
    M0 = fmaxf(M0, ML[((size_t)bh*SP + s)*16 + i0]);
    M1 = fmaxf(M1, ML[((size_t)bh*SP + s)*16 + i1]);
  }
  float L0 = 0.f, L1 = 0.f, o0 = 0.f, o1 = 0.f;
  for (int s = 0; s < SP; ++s) {
    const float w0 = __expf(ML[((size_t)bh*SP + s)*16 + i0] - M0);
    const float w1 = __expf(ML[((size_t)bh*SP + s)*16 + i1] - M1);
    L0 += w0 * ML[((size_t)bh*SP + s)*16 + 8 + i0];
    L1 += w1 * ML[((size_t)bh*SP + s)*16 + 8 + i1];
    o0 += w0 * Opart[(((size_t)bh*SP + s)*8 + i0)*64 + d];
    o1 += w1 * Opart[(((size_t)bh*SP + s)*8 + i1)*64 + d];
  }
  outT[((size_t)(h*DH_ + d))*M_ + b*TQ_ + i0] = o0 / L0;
  outT[((size_t)(h*DH_ + d))*M_ + b*TQ_ + i1] = o1 / L1;
}

extern "C" void kernel_launch(void* const* d_in, const int* in_sizes, int n_in,
                              void* d_out, int out_size, void* d_ws, size_t ws_size,
                              hipStream_t stream)
{
  (void)in_sizes; (void)n_in; (void)out_size; (void)ws_size;
  const float* x    = (const float*)d_in[0];
  const float* skc  = (const float*)d_in[1];
  const float* svc  = (const float*)d_in[2];
  const float* ck   = (const float*)d_in[3];
  const float* cv   = (const float*)d_in[4];
  const float* msk  = (const float*)d_in[5];
  const float* wq   = (const float*)d_in[6];
  const float* bq   = (const float*)d_in[7];
  const float* wk   = (const float*)d_in[8];
  const float* wvv  = (const float*)d_in[9];
  const float* bv   = (const float*)d_in[10];
  const float* wo   = (const float*)d_in[11];
  const float* bo   = (const float*)d_in[12];
  const float* cwq  = (const float*)d_in[13];
  const float* cbq  = (const float*)d_in[14];
  const float* cwo  = (const float*)d_in[15];
  const float* cbo  = (const float*)d_in[16];
  const float* ln1w = (const float*)d_in[17];
  const float* ln1b = (const float*)d_in[18];
  const float* ln2w = (const float*)d_in[19];
  const float* ln2b = (const float*)d_in[20];
  const float* ln3w = (const float*)d_in[21];
  const float* ln3b = (const float*)d_in[22];
  const float* w1   = (const float*)d_in[23];
  const float* b1   = (const float*)d_in[24];
  const float* w2   = (const float*)d_in[25];
  const float* b2   = (const float*)d_in[26];
  // d_in[27] = offset (int) — fixed at TP_ here.

  float* out_x  = (float*)d_out;
  float* out_k1 = out_x + 81920;
  float* out_v1 = out_x + 163840;

  float* ws = (float*)d_ws;
  float* xlT  = ws + 0;               // [1280][64], reused 3x
  float* qbuf = ws + 81920;           // q / qc row-major [64][1280]
  float* k1f  = ws + 163840;
  float* v1f  = ws + 245760;
  float* x2   = ws + 327680;
  float* x3   = ws + 409600;
  float* attT = ws + 491520;          // attn out transposed, reused 2x
  float* hT   = ws + 573440;          // [5120][64]
  float* Pg   = ws + 901120;          // split-K partials / attention Opart
  float* Pq   = Pg;
  float* Pk   = Pg + 819200;
  float* Pv   = Pg + 1638400;
  float* MLS  = ws + 4177920;         // 160*8*16
  float* MLC  = ws + 4218880;         // 160*24*16

  const dim3 blk(256);

  // --- self-attention ---
  ln_kernel<<<dim3(64), blk, 0, stream>>>(x, ln1w, ln1b, xlT);
  gemm_splitk<<<dim3(10,10,3), blk, 0, stream>>>(xlT, wq, wk, wvv, Pq, Pk, Pv, 1280, 128);
  epilogue_qkv<<<dim3(320,1,3), blk, 0, stream>>>(Pq, Pk, Pv, bq, bv, qbuf, k1f, v1f, out_k1, out_v1);
  // SP=8, chunk=57 (8*57=456 >= 455)
  attn_fused<<<dim3(8,20,8), blk, 0, stream>>>(qbuf, skc, k1f, svc, v1f, msk, Pg, MLS, 455, 447, 57);
  attn_pv_combine<<<dim3(20,8), blk, 0, stream>>>(Pg, MLS, attT, 8);
  gemm_splitk<<<dim3(10,10,1), blk, 0, stream>>>(attT, wo, wo, wo, Pq, Pq, Pq, 1280, 128);
  epilogue_ln<<<dim3(64), blk, 0, stream>>>(Pq, 10, bo, x, ln2w, ln2b, x2, xlT);

  // --- cross-attention ---
  gemm_splitk<<<dim3(10,10,1), blk, 0, stream>>>(xlT, cwq, cwq, cwq, Pq, Pq, Pq, 1280, 128);
  epilogue_kernel<<<dim3(320), blk, 0, stream>>>(Pq, 10, 1280, cbq, nullptr, 0, qbuf, nullptr, nullptr);
  // SP=24, chunk=64 (23*64=1472, last split 28 rows)
  attn_fused<<<dim3(24,20,8), blk, 0, stream>>>(qbuf, ck, nullptr, cv, nullptr, nullptr, Pg, MLC, 1500, 1500, 64);
  attn_pv_combine<<<dim3(20,8), blk, 0, stream>>>(Pg, MLC, attT, 24);
  gemm_splitk<<<dim3(10,10,1), blk, 0, stream>>>(attT, cwo, cwo, cwo, Pq, Pq, Pq, 1280, 128);
  epilogue_ln<<<dim3(64), blk, 0, stream>>>(Pq, 10, cbo, x2, ln3w, ln3b, x3, xlT);

  // --- MLP ---
  gemm_splitk<<<dim3(40,10,1), blk, 0, stream>>>(xlT, w1, w1, w1, Pg, Pg, Pg, 5120, 128);
  epilogue_kernel<<<dim3(1280), blk, 0, stream>>>(Pg, 10, 5120, b1, nullptr, 1, nullptr, hT, nullptr);
  gemm_splitk<<<dim3(10,40,1), blk, 0, stream>>>(hT, w2, w2, w2, Pg, Pg, Pg, 1280, 128);
  epilogue_kernel<<<dim3(320), blk, 0, stream>>>(Pg, 40, 1280, b2, x3, 0, nullptr, nullptr, out_x);
}

// Round 4
// 409.753 us; speedup vs baseline: 1.5006x; 1.4499x over previous
//
#include <hip/hip_runtime.h>
#include <hip/hip_bf16.h>

#define B_   8
#define TQ_  8
#define TP_  447
#define TC_  1500
#define D_   1280
#define H_   20
#define DH_  64
#define DFF_ 5120
#define M_   64    // B_*TQ_ total rows

// ================= LayerNorm: row-major fp32 input -> transposed f32 [D_][M_]
__global__ __launch_bounds__(256) void ln_kernel(const float* __restrict__ X,
    const float* __restrict__ g, const float* __restrict__ be, float* __restrict__ outT)
{
  __shared__ float redA[4], redB[4];
  const int m = blockIdx.x;
  const int tid = threadIdx.x;
  float v[5];
#pragma unroll
  for (int t = 0; t < 5; ++t) v[t] = X[(size_t)m*D_ + tid + t*256];
  float s = v[0]+v[1]+v[2]+v[3]+v[4];
#pragma unroll
  for (int o = 32; o; o >>= 1) s += __shfl_down(s, o, 64);
  if ((tid & 63) == 0) redA[tid >> 6] = s;
  __syncthreads();
  const float mean = (redA[0]+redA[1]+redA[2]+redA[3]) * (1.0f/D_);
  float q = 0.f;
#pragma unroll
  for (int t = 0; t < 5; ++t) { const float d = v[t]-mean; q += d*d; }
#pragma unroll
  for (int o = 32; o; o >>= 1) q += __shfl_down(q, o, 64);
  if ((tid & 63) == 0) redB[tid >> 6] = q;
  __syncthreads();
  const float rstd = rsqrtf((redB[0]+redB[1]+redB[2]+redB[3]) * (1.0f/D_) + 1e-5f);
#pragma unroll
  for (int t = 0; t < 5; ++t) {
    const int c = tid + t*256;
    outT[(size_t)c*M_ + m] = (v[t]-mean)*rstd*g[c] + be[c];
  }
}

// ================= split-K GEMM: P[s][m][n] = sum_{k in chunk s} XT[k][m]*W[k][n]
// R4: W tile staged in LDS (8 independent coalesced float4 loads/thread) — the
// old per-kk direct-global W load was a dependency-chained cold-HBM miss every
// iteration with ~1 wave/SIMD occupancy (100-block grids): latency-serialized.
// LDS = 16KB xs + 32KB wsh = 48KB -> 3 blocks/CU.
__global__ __launch_bounds__(256) void gemm_splitk(
    const float* __restrict__ XT,
    const float* __restrict__ Wa, const float* __restrict__ Wb, const float* __restrict__ Wc,
    float* __restrict__ Pa, float* __restrict__ Pb, float* __restrict__ Pc,
    int N, int chunk)
{
  __shared__ float xs[64][64];     // 16 KB
  __shared__ float wsh[64][128];   // 32 KB
  const int z = blockIdx.z;
  const float* W = (z == 0 ? Wa : (z == 1 ? Wb : Wc));
  float* P = (z == 0 ? Pa : (z == 1 ? Pb : Pc));
  const int tid  = threadIdx.x;
  const int lane = tid & 63;
  const int wv   = tid >> 6;
  const int n    = blockIdx.x*128 + lane*2;
  const int k0   = blockIdx.y * chunk;
  float accL[16], accH[16];
#pragma unroll
  for (int r = 0; r < 16; ++r) { accL[r] = 0.f; accH[r] = 0.f; }

  for (int kb = 0; kb < chunk; kb += 64) {
    __syncthreads();
    // stage XT tile: 64 rows x 64 m, 4 float4/thread, contiguous
    {
      const float4* src = (const float4*)(XT + (size_t)(k0 + kb)*M_);
      float4* dst = (float4*)&xs[0][0];
#pragma unroll
      for (int i = 0; i < 4; ++i) dst[tid + i*256] = src[tid + i*256];
    }
    // stage W tile: 64 rows x 128 n, 8 float4/thread, 512B-coalesced per row
    {
      const float* Wb0 = W + (size_t)(k0 + kb)*N + blockIdx.x*128;
#pragma unroll
      for (int i = 0; i < 8; ++i) {
        const int idx = tid + i*256;            // 0..2047 float4 slots
        const int r = idx >> 5, c = (idx & 31)*4;
        *(float4*)&wsh[r][c] = *(const float4*)(Wb0 + (size_t)r*N + c);
      }
    }
    __syncthreads();
    for (int kk = 0; kk < 64; ++kk) {
      const float2 wp = *(const float2*)&wsh[kk][lane*2];  // 2-way alias: free
      const float wl = wp.x;
      const float wh = wp.y;
      const float* xr = &xs[kk][wv*16];                    // wave-broadcast
#pragma unroll
      for (int r4 = 0; r4 < 4; ++r4) {
        const float4 xv = *(const float4*)(xr + r4*4);
        accL[r4*4+0] += xv.x*wl; accH[r4*4+0] += xv.x*wh;
        accL[r4*4+1] += xv.y*wl; accH[r4*4+1] += xv.y*wh;
        accL[r4*4+2] += xv.z*wl; accH[r4*4+2] += xv.z*wh;
        accL[r4*4+3] += xv.w*wl; accH[r4*4+3] += xv.w*wh;
      }
    }
  }
#pragma unroll
  for (int r = 0; r < 16; ++r) {
    const int m = wv*16 + r;
    float2 st; st.x = accL[r]; st.y = accH[r];
    *(float2*)(P + ((size_t)blockIdx.y*M_ + m)*N + n) = st;
  }
}

// ================= epilogue: sum split-K partials, +bias, gelu, +residual, multi-format out
// S templated so the partial loop fully unrolls into independent loads.
template<int S>
__global__ __launch_bounds__(256) void epilogue_kernel(
    const float* __restrict__ P, int N,
    const float* __restrict__ bias,
    const float* __restrict__ res,
    int gelu,
    float* __restrict__ outA, float* __restrict__ outT, float* __restrict__ outB)
{
  const int idx = blockIdx.x*256 + threadIdx.x;   // < M_*N
  const int m = idx / N;
  const int n = idx - m*N;
  float a = 0.f;
#pragma unroll
  for (int s = 0; s < S; ++s) a += P[((size_t)s*M_ + m)*N + n];
  if (bias) a += bias[n];
  if (gelu) a = 0.5f*a*(1.0f + erff(a*0.70710678118654752f));
  if (res) a += res[idx];
  if (outA) outA[idx] = a;
  if (outT) outT[(size_t)n*M_ + m] = a;
  if (outB) outB[idx] = a;
}

// ================= fused epilogue (sum partials + bias + residual) + LayerNorm
template<int S>
__global__ __launch_bounds__(256) void epilogue_ln(
    const float* __restrict__ P,
    const float* __restrict__ bias, const float* __restrict__ res,
    const float* __restrict__ g, const float* __restrict__ be,
    float* __restrict__ outRow, float* __restrict__ outT)
{
  __shared__ float redA[4], redB[4];
  const int m = blockIdx.x;
  const int tid = threadIdx.x;
  float v[5];
#pragma unroll
  for (int t = 0; t < 5; ++t) {
    const int c = tid + t*256;
    float a = 0.f;
#pragma unroll
    for (int s = 0; s < S; ++s) a += P[((size_t)s*M_ + m)*D_ + c];
    a += bias[c] + res[(size_t)m*D_ + c];
    outRow[(size_t)m*D_ + c] = a;
    v[t] = a;
  }
  float s = v[0]+v[1]+v[2]+v[3]+v[4];
#pragma unroll
  for (int o = 32; o; o >>= 1) s += __shfl_down(s, o, 64);
  if ((tid & 63) == 0) redA[tid >> 6] = s;
  __syncthreads();
  const float mean = (redA[0]+redA[1]+redA[2]+redA[3]) * (1.0f/D_);
  float q = 0.f;
#pragma unroll
  for (int t = 0; t < 5; ++t) { const float d = v[t]-mean; q += d*d; }
#pragma unroll
  for (int o = 32; o; o >>= 1) q += __shfl_down(q, o, 64);
  if ((tid & 63) == 0) redB[tid >> 6] = q;
  __syncthreads();
  const float rstd = rsqrtf((redB[0]+redB[1]+redB[2]+redB[3]) * (1.0f/D_) + 1e-5f);
#pragma unroll
  for (int t = 0; t < 5; ++t) {
    const int c = tid + t*256;
    outT[(size_t)c*M_ + m] = (v[t]-mean)*rstd*g[c] + be[c];
  }
}

// ================= z-batched QKV epilogue: sum 10 partials, per-z bias/outputs
__global__ __launch_bounds__(256) void epilogue_qkv(
    const float* __restrict__ Pq, const float* __restrict__ Pk, const float* __restrict__ Pv,
    const float* __restrict__ bq, const float* __restrict__ bv,
    float* __restrict__ qbuf, float* __restrict__ k1f, float* __restrict__ v1f,
    float* __restrict__ out_k1, float* __restrict__ out_v1)
{
  const int z = blockIdx.z;
  const int idx = blockIdx.x*256 + threadIdx.x;   // < M_*D_
  const float* P = (z == 0 ? Pq : (z == 1 ? Pk : Pv));
  float a = 0.f;
#pragma unroll
  for (int s = 0; s < 10; ++s) a += P[(size_t)s*M_*D_ + idx];
  const int n = idx % D_;
  if (z == 0)      { a += bq[n]; qbuf[idx] = a; }
  else if (z == 1) { k1f[idx] = a; out_k1[idx] = a; }
  else             { a += bv[n]; v1f[idx] = a; out_v1[idx] = a; }
}

// ================= fused attention split: scores + softmax (LDS) + PV partial
// grid (SP, H_, B_), block 256. chunk <= 64.  (unchanged from R3)
#define SCS 10
__global__ __launch_bounds__(256, 7) void attn_fused(
    const float* __restrict__ Q,
    const float* __restrict__ Kc, const float* __restrict__ Kn,
    const float* __restrict__ Vc, const float* __restrict__ Vn,
    const float* __restrict__ mask,
    float* __restrict__ Opart, float* __restrict__ ML,
    int TK, int TPp, int chunk)
{
  __shared__ float sc[64*SCS];      // scores then exp-weights, [jl][SCS]  (2.5KB)
  __shared__ float qs[8*64];        // q rows for this (b,*,h)             (2KB)
  __shared__ float kr[64*68];       // K tile [row][68] (phase 0/1) == red (phase 3) (17KB)
  const int tid = threadIdx.x;
  const int sp = blockIdx.x, h = blockIdx.y, b = blockIdx.z;
  const int SP = gridDim.x;
  const int j0 = sp * chunk;
  const int cnt = min(chunk, TK - j0);
  const int bh = b*H_ + h;

  // stage q: 512 floats (coalesced, lane=d)
  {
    const int i = tid >> 6, d = tid & 63;
    qs[tid]       = Q[((size_t)(b*TQ_ + i    ))*D_ + h*DH_ + d];
    qs[tid + 256] = Q[((size_t)(b*TQ_ + i + 4))*D_ + h*DH_ + d];
  }
  // stage K tile: cnt rows x 64 dims, coalesced float4 (16 lanes per row)
  for (int u = tid; u < cnt*16; u += 256) {
    const int r = u >> 4, c = u & 15;
    const int j = j0 + r;
    const float* kg = (j < TPp)
      ? Kc + ((size_t)b*TPp + j)*D_ + h*DH_
      : Kn + ((size_t)(b*TQ_ + (j - TPp)))*D_ + h*DH_;
    *(float4*)&kr[r*68 + c*4] = *(const float4*)(kg + c*4);
  }
  __syncthreads();

  // ---- phase 1: scores; 4 threads per key row (16 dims each), shfl_xor combine ----
  {
    const int jl = tid >> 2, qt = tid & 3;
    if (jl < cnt) {
      const float* krow = &kr[jl*68 + qt*16];
      const float4 k0 = *(const float4*)(krow);
      const float4 k1 = *(const float4*)(krow + 4);
      const float4 k2 = *(const float4*)(krow + 8);
      const float4 k3 = *(const float4*)(krow + 12);
      float acc[8];
#pragma unroll
      for (int i = 0; i < 8; ++i) {
        const float* qp = &qs[i*64 + qt*16];
        const float4 q0 = *(const float4*)(qp);
        const float4 q1 = *(const float4*)(qp + 4);
        const float4 q2 = *(const float4*)(qp + 8);
        const float4 q3 = *(const float4*)(qp + 12);
        acc[i] = q0.x*k0.x + q0.y*k0.y + q0.z*k0.z + q0.w*k0.w
               + q1.x*k1.x + q1.y*k1.y + q1.z*k1.z + q1.w*k1.w
               + q2.x*k2.x + q2.y*k2.y + q2.z*k2.z + q2.w*k2.w
               + q3.x*k3.x + q3.y*k3.y + q3.z*k3.z + q3.w*k3.w;
      }
#pragma unroll
      for (int i = 0; i < 8; ++i) {
        acc[i] += __shfl_xor(acc[i], 1, 64);
        acc[i] += __shfl_xor(acc[i], 2, 64);
      }
      if (qt == 0) {
        const int j = j0 + jl;
#pragma unroll
        for (int i = 0; i < 8; ++i) {
          float vv = acc[i]*0.125f;       // (dh^-0.25)^2 on the q.k product
          if (mask) vv += mask[(size_t)i*TK + j];
          sc[jl*SCS + i] = vv;
        }
      }
    }
  }
  __syncthreads();

  // ---- phase 2: per-split softmax, exp in place; 8 row-groups x 32 lanes ----
  {
    const int g = tid >> 5, l = tid & 31;
    float mx = -3.0e38f;
    for (int jl = l; jl < cnt; jl += 32) mx = fmaxf(mx, sc[jl*SCS + g]);
#pragma unroll
    for (int o = 16; o; o >>= 1) mx = fmaxf(mx, __shfl_down(mx, o, 32));
    mx = __shfl(mx, 0, 32);
    float sum = 0.f;
    for (int jl = l; jl < cnt; jl += 32) {
      const float e = __expf(sc[jl*SCS + g] - mx);
      sc[jl*SCS + g] = e;
      sum += e;
    }
#pragma unroll
    for (int o = 16; o; o >>= 1) sum += __shfl_down(sum, o, 32);
    if (l == 0) {
      ML[((size_t)bh*SP + sp)*16 + g]     = mx;
      ML[((size_t)bh*SP + sp)*16 + 8 + g] = sum;
    }
  }
  __syncthreads();

  // ---- phase 3: PV. Waves interleave over j (V read ONCE per block, 256B/instr);
  //      lane = d; all 8 q-rows accumulated per lane; LDS-broadcast weights ----
  {
    const int wv = tid >> 6;
    const int d  = tid & 63;
    float acc[8] = {0.f,0.f,0.f,0.f,0.f,0.f,0.f,0.f};
#pragma unroll 4
    for (int jl = wv; jl < cnt; jl += 4) {
      const int j = j0 + jl;
      const float vv = (j < TPp)
        ? Vc[((size_t)b*TPp + j)*D_ + h*DH_ + d]
        : Vn[((size_t)(b*TQ_ + (j - TPp)))*D_ + h*DH_ + d];
      const float2 p0 = *(const float2*)&sc[jl*SCS + 0];   // broadcast, conflict-free
      const float2 p1 = *(const float2*)&sc[jl*SCS + 2];
      const float2 p2 = *(const float2*)&sc[jl*SCS + 4];
      const float2 p3 = *(const float2*)&sc[jl*SCS + 6];
      acc[0] += p0.x*vv; acc[1] += p0.y*vv;
      acc[2] += p1.x*vv; acc[3] += p1.y*vv;
      acc[4] += p2.x*vv; acc[5] += p2.y*vv;
      acc[6] += p3.x*vv; acc[7] += p3.y*vv;
    }
#pragma unroll
    for (int i = 0; i < 8; ++i) kr[(wv*8 + i)*64 + d] = acc[i];
  }
  __syncthreads();
  {
#pragma unroll
    for (int t = 0; t < 2; ++t) {
      const int o = tid + t*256;        // < 512
      const int i = o >> 6, d = o & 63;
      const float r = kr[(0*8 + i)*64 + d] + kr[(1*8 + i)*64 + d]
                    + kr[(2*8 + i)*64 + d] + kr[(3*8 + i)*64 + d];
      Opart[(((size_t)bh*SP + sp)*8 + i)*64 + d] = r;
    }
  }
}

// ================= merge PV partials with split-softmax weights; outT f32 [D_][M_]
__global__ __launch_bounds__(256) void attn_pv_combine(
    const float* __restrict__ Opart, const float* __restrict__ ML,
    float* __restrict__ outT, int SP)
{
  const int tid = threadIdx.x;
  const int h = blockIdx.x, b = blockIdx.y;
  const int bh = b*H_ + h;
  const int wv = tid >> 6, d = tid & 63;
  const int i0 = wv*2, i1 = i0 + 1;
  float M0 = -3.0e38f, M1 = -3.0e38f;
  for (int s = 0; s < SP; ++s) {
    M0 = fmaxf(M0, ML[((size_t)bh*SP + s)*16 + i0]);
    M1 = fmaxf(M1, ML[((size_t)bh*SP + s)*16 + i1]);
  }
  float L0 = 0.f, L1 = 0.f, o0 = 0.f, o1 = 0.f;
  for (int s = 0; s < SP; ++s) {
    const float w0 = __expf(ML[((size_t)bh*SP + s)*16 + i0] - M0);
    const float w1 = __expf(ML[((size_t)bh*SP + s)*16 + i1] - M1);
    L0 += w0 * ML[((size_t)bh*SP + s)*16 + 8 + i0];
    L1 += w1 * ML[((size_t)bh*SP + s)*16 + 8 + i1];
    o0 += w0 * Opart[(((size_t)bh*SP + s)*8 + i0)*64 + d];
    o1 += w1 * Opart[(((size_t)bh*SP + s)*8 + i1)*64 + d];
  }
  outT[((size_t)(h*DH_ + d))*M_ + b*TQ_ + i0] = o0 / L0;
  outT[((size_t)(h*DH_ + d))*M_ + b*TQ_ + i1] = o1 / L1;
}

extern "C" void kernel_launch(void* const* d_in, const int* in_sizes, int n_in,
                              void* d_out, int out_size, void* d_ws, size_t ws_size,
                              hipStream_t stream)
{
  (void)in_sizes; (void)n_in; (void)out_size; (void)ws_size;
  const float* x    = (const float*)d_in[0];
  const float* skc  = (const float*)d_in[1];
  const float* svc  = (const float*)d_in[2];
  const float* ck   = (const float*)d_in[3];
  const float* cv   = (const float*)d_in[4];
  const float* msk  = (const float*)d_in[5];
  const float* wq   = (const float*)d_in[6];
  const float* bq   = (const float*)d_in[7];
  const float* wk   = (const float*)d_in[8];
  const float* wvv  = (const float*)d_in[9];
  const float* bv   = (const float*)d_in[10];
  const float* wo   = (const float*)d_in[11];
  const float* bo   = (const float*)d_in[12];
  const float* cwq  = (const float*)d_in[13];
  const float* cbq  = (const float*)d_in[14];
  const float* cwo  = (const float*)d_in[15];
  const float* cbo  = (const float*)d_in[16];
  const float* ln1w = (const float*)d_in[17];
  const float* ln1b = (const float*)d_in[18];
  const float* ln2w = (const float*)d_in[19];
  const float* ln2b = (const float*)d_in[20];
  const float* ln3w = (const float*)d_in[21];
  const float* ln3b = (const float*)d_in[22];
  const float* w1   = (const float*)d_in[23];
  const float* b1   = (const float*)d_in[24];
  const float* w2   = (const float*)d_in[25];
  const float* b2   = (const float*)d_in[26];
  // d_in[27] = offset (int) — fixed at TP_ here.

  float* out_x  = (float*)d_out;
  float* out_k1 = out_x + 81920;
  float* out_v1 = out_x + 163840;

  float* ws = (float*)d_ws;
  float* xlT  = ws + 0;               // [1280][64], reused 3x
  float* qbuf = ws + 81920;           // q / qc row-major [64][1280]
  float* k1f  = ws + 163840;
  float* v1f  = ws + 245760;
  float* x2   = ws + 327680;
  float* x3   = ws + 409600;
  float* attT = ws + 491520;          // attn out transposed, reused 2x
  float* hT   = ws + 573440;          // [5120][64]
  float* Pg   = ws + 901120;          // split-K partials / attention Opart
  float* Pq   = Pg;
  float* Pk   = Pg + 819200;
  float* Pv   = Pg + 1638400;
  float* MLS  = ws + 4177920;         // 160*8*16
  float* MLC  = ws + 4218880;         // 160*24*16

  const dim3 blk(256);

  // --- self-attention ---
  ln_kernel<<<dim3(64), blk, 0, stream>>>(x, ln1w, ln1b, xlT);
  gemm_splitk<<<dim3(10,10,3), blk, 0, stream>>>(xlT, wq, wk, wvv, Pq, Pk, Pv, 1280, 128);
  epilogue_qkv<<<dim3(320,1,3), blk, 0, stream>>>(Pq, Pk, Pv, bq, bv, qbuf, k1f, v1f, out_k1, out_v1);
  // SP=8, chunk=57 (8*57=456 >= 455)
  attn_fused<<<dim3(8,20,8), blk, 0, stream>>>(qbuf, skc, k1f, svc, v1f, msk, Pg, MLS, 455, 447, 57);
  attn_pv_combine<<<dim3(20,8), blk, 0, stream>>>(Pg, MLS, attT, 8);
  // wo: 20-way split-K (chunk 64) for 200-block parallelism; partials span Pq..Pk ok
  gemm_splitk<<<dim3(10,20,1), blk, 0, stream>>>(attT, wo, wo, wo, Pq, Pq, Pq, 1280, 64);
  epilogue_ln<20><<<dim3(64), blk, 0, stream>>>(Pq, bo, x, ln2w, ln2b, x2, xlT);

  // --- cross-attention ---
  gemm_splitk<<<dim3(10,20,1), blk, 0, stream>>>(xlT, cwq, cwq, cwq, Pq, Pq, Pq, 1280, 64);
  epilogue_kernel<20><<<dim3(320), blk, 0, stream>>>(Pq, 1280, cbq, nullptr, 0, qbuf, nullptr, nullptr);
  // SP=24, chunk=64 (23*64=1472, last split 28 rows)
  attn_fused<<<dim3(24,20,8), blk, 0, stream>>>(qbuf, ck, nullptr, cv, nullptr, nullptr, Pg, MLC, 1500, 1500, 64);
  attn_pv_combine<<<dim3(20,8), blk, 0, stream>>>(Pg, MLC, attT, 24);
  gemm_splitk<<<dim3(10,20,1), blk, 0, stream>>>(attT, cwo, cwo, cwo, Pq, Pq, Pq, 1280, 64);
  epilogue_ln<20><<<dim3(64), blk, 0, stream>>>(Pq, cbo, x2, ln3w, ln3b, x3, xlT);

  // --- MLP ---
  gemm_splitk<<<dim3(40,10,1), blk, 0, stream>>>(xlT, w1, w1, w1, Pg, Pg, Pg, 5120, 128);
  epilogue_kernel<10><<<dim3(1280), blk, 0, stream>>>(Pg, 5120, b1, nullptr, 1, nullptr, hT, nullptr);
  gemm_splitk<<<dim3(10,40,1), blk, 0, stream>>>(hT, w2, w2, w2, Pg, Pg, Pg, 1280, 128);
  epilogue_kernel<40><<<dim3(320), blk, 0, stream>>>(Pg, 1280, b2, x3, 0, nullptr, nullptr, out_x);
}

// Round 5
// 400.629 us; speedup vs baseline: 1.5348x; 1.0228x over previous
//
#include <hip/hip_runtime.h>
#include <hip/hip_bf16.h>

#define B_   8
#define TQ_  8
#define TP_  447
#define TC_  1500
#define D_   1280
#define H_   20
#define DH_  64
#define DFF_ 5120
#define M_   64    // B_*TQ_ total rows

// ================= LayerNorm: row-major fp32 in -> ROW-major normed out (coalesced)
__global__ __launch_bounds__(256) void ln_kernel(const float* __restrict__ X,
    const float* __restrict__ g, const float* __restrict__ be, float* __restrict__ out)
{
  __shared__ float redA[4], redB[4];
  const int m = blockIdx.x;
  const int tid = threadIdx.x;
  float v[5];
#pragma unroll
  for (int t = 0; t < 5; ++t) v[t] = X[(size_t)m*D_ + tid + t*256];
  float s = v[0]+v[1]+v[2]+v[3]+v[4];
#pragma unroll
  for (int o = 32; o; o >>= 1) s += __shfl_down(s, o, 64);
  if ((tid & 63) == 0) redA[tid >> 6] = s;
  __syncthreads();
  const float mean = (redA[0]+redA[1]+redA[2]+redA[3]) * (1.0f/D_);
  float q = 0.f;
#pragma unroll
  for (int t = 0; t < 5; ++t) { const float d = v[t]-mean; q += d*d; }
#pragma unroll
  for (int o = 32; o; o >>= 1) q += __shfl_down(q, o, 64);
  if ((tid & 63) == 0) redB[tid >> 6] = q;
  __syncthreads();
  const float rstd = rsqrtf((redB[0]+redB[1]+redB[2]+redB[3]) * (1.0f/D_) + 1e-5f);
#pragma unroll
  for (int t = 0; t < 5; ++t) {
    const int c = tid + t*256;
    out[(size_t)m*D_ + c] = (v[t]-mean)*rstd*g[c] + be[c];
  }
}

// ================= split-K GEMM: P[s][m][n] = sum_k A[m][k]*W[k][n]
// A is ROW-major (lda param); transpose happens during LDS staging (64x256B
// segment reads, fully-consumed lines; 4-way LDS write alias ~1.58x, cheap).
// This lets every producer kernel write coalesced row-major.
__global__ __launch_bounds__(256) void gemm_splitk(
    const float* __restrict__ A, int lda,
    const float* __restrict__ Wa, const float* __restrict__ Wb, const float* __restrict__ Wc,
    float* __restrict__ Pa, float* __restrict__ Pb, float* __restrict__ Pc,
    int N, int chunk)
{
  __shared__ float xs[64][64];     // 16 KB, [k][m]
  __shared__ float wsh[64][128];   // 32 KB
  const int z = blockIdx.z;
  const float* W = (z == 0 ? Wa : (z == 1 ? Wb : Wc));
  float* P = (z == 0 ? Pa : (z == 1 ? Pb : Pc));
  const int tid  = threadIdx.x;
  const int lane = tid & 63;
  const int wv   = tid >> 6;
  const int n    = blockIdx.x*128 + lane*2;
  const int k0   = blockIdx.y * chunk;
  const int mrow = tid >> 2;          // 0..63
  const int ks   = (tid & 3) * 16;    // 0,16,32,48
  float accL[16], accH[16];
#pragma unroll
  for (int r = 0; r < 16; ++r) { accL[r] = 0.f; accH[r] = 0.f; }

  for (int kb = 0; kb < chunk; kb += 64) {
    __syncthreads();
    // stage A tile with transpose: A[mrow][k0+kb+ks .. +16] -> xs[k][m]
    {
      const float4* arow = (const float4*)(A + (size_t)mrow*lda + k0 + kb + ks);
#pragma unroll
      for (int i = 0; i < 4; ++i) {
        const float4 av = arow[i];
        const int kk = ks + i*4;
        xs[kk+0][mrow] = av.x;
        xs[kk+1][mrow] = av.y;
        xs[kk+2][mrow] = av.z;
        xs[kk+3][mrow] = av.w;
      }
    }
    // stage W tile: 64 rows x 128 n, 8 float4/thread, 512B-coalesced per row
    {
      const float* Wb0 = W + (size_t)(k0 + kb)*N + blockIdx.x*128;
#pragma unroll
      for (int i = 0; i < 8; ++i) {
        const int idx = tid + i*256;            // 0..2047 float4 slots
        const int r = idx >> 5, c = (idx & 31)*4;
        *(float4*)&wsh[r][c] = *(const float4*)(Wb0 + (size_t)r*N + c);
      }
    }
    __syncthreads();
    for (int kk = 0; kk < 64; ++kk) {
      const float2 wp = *(const float2*)&wsh[kk][lane*2];  // 2-way alias: free
      const float wl = wp.x;
      const float wh = wp.y;
      const float* xr = &xs[kk][wv*16];                    // wave-broadcast
#pragma unroll
      for (int r4 = 0; r4 < 4; ++r4) {
        const float4 xv = *(const float4*)(xr + r4*4);
        accL[r4*4+0] += xv.x*wl; accH[r4*4+0] += xv.x*wh;
        accL[r4*4+1] += xv.y*wl; accH[r4*4+1] += xv.y*wh;
        accL[r4*4+2] += xv.z*wl; accH[r4*4+2] += xv.z*wh;
        accL[r4*4+3] += xv.w*wl; accH[r4*4+3] += xv.w*wh;
      }
    }
  }
#pragma unroll
  for (int r = 0; r < 16; ++r) {
    const int m = wv*16 + r;
    float2 st; st.x = accL[r]; st.y = accH[r];
    *(float2*)(P + ((size_t)blockIdx.y*M_ + m)*N + n) = st;
  }
}

// ================= epilogue: sum split-K partials, +bias, gelu, +residual; row-major outs
template<int S>
__global__ __launch_bounds__(256) void epilogue_kernel(
    const float* __restrict__ P, int N,
    const float* __restrict__ bias,
    const float* __restrict__ res,
    int gelu,
    float* __restrict__ outA, float* __restrict__ outB)
{
  const int idx = blockIdx.x*256 + threadIdx.x;   // < M_*N
  const int m = idx / N;
  const int n = idx - m*N;
  float a = 0.f;
#pragma unroll
  for (int s = 0; s < S; ++s) a += P[((size_t)s*M_ + m)*N + n];
  if (bias) a += bias[n];
  if (gelu) a = 0.5f*a*(1.0f + erff(a*0.70710678118654752f));
  if (res) a += res[idx];
  if (outA) outA[idx] = a;
  if (outB) outB[idx] = a;
}

// ================= fused epilogue (sum partials + bias + residual) + LayerNorm
// both outputs row-major (coalesced)
template<int S>
__global__ __launch_bounds__(256) void epilogue_ln(
    const float* __restrict__ P,
    const float* __restrict__ bias, const float* __restrict__ res,
    const float* __restrict__ g, const float* __restrict__ be,
    float* __restrict__ outRow, float* __restrict__ outLN)
{
  __shared__ float redA[4], redB[4];
  const int m = blockIdx.x;
  const int tid = threadIdx.x;
  float v[5];
#pragma unroll
  for (int t = 0; t < 5; ++t) {
    const int c = tid + t*256;
    float a = 0.f;
#pragma unroll
    for (int s = 0; s < S; ++s) a += P[((size_t)s*M_ + m)*D_ + c];
    a += bias[c] + res[(size_t)m*D_ + c];
    outRow[(size_t)m*D_ + c] = a;
    v[t] = a;
  }
  float s = v[0]+v[1]+v[2]+v[3]+v[4];
#pragma unroll
  for (int o = 32; o; o >>= 1) s += __shfl_down(s, o, 64);
  if ((tid & 63) == 0) redA[tid >> 6] = s;
  __syncthreads();
  const float mean = (redA[0]+redA[1]+redA[2]+redA[3]) * (1.0f/D_);
  float q = 0.f;
#pragma unroll
  for (int t = 0; t < 5; ++t) { const float d = v[t]-mean; q += d*d; }
#pragma unroll
  for (int o = 32; o; o >>= 1) q += __shfl_down(q, o, 64);
  if ((tid & 63) == 0) redB[tid >> 6] = q;
  __syncthreads();
  const float rstd = rsqrtf((redB[0]+redB[1]+redB[2]+redB[3]) * (1.0f/D_) + 1e-5f);
#pragma unroll
  for (int t = 0; t < 5; ++t) {
    const int c = tid + t*256;
    outLN[(size_t)m*D_ + c] = (v[t]-mean)*rstd*g[c] + be[c];
  }
}

// ================= z-batched QKV epilogue: sum 10 partials, per-z bias/outputs
__global__ __launch_bounds__(256) void epilogue_qkv(
    const float* __restrict__ Pq, const float* __restrict__ Pk, const float* __restrict__ Pv,
    const float* __restrict__ bq, const float* __restrict__ bv,
    float* __restrict__ qbuf, float* __restrict__ k1f, float* __restrict__ v1f,
    float* __restrict__ out_k1, float* __restrict__ out_v1)
{
  const int z = blockIdx.z;
  const int idx = blockIdx.x*256 + threadIdx.x;   // < M_*D_
  const float* P = (z == 0 ? Pq : (z == 1 ? Pk : Pv));
  float a = 0.f;
#pragma unroll
  for (int s = 0; s < 10; ++s) a += P[(size_t)s*M_*D_ + idx];
  const int n = idx % D_;
  if (z == 0)      { a += bq[n]; qbuf[idx] = a; }
  else if (z == 1) { k1f[idx] = a; out_k1[idx] = a; }
  else             { a += bv[n]; v1f[idx] = a; out_v1[idx] = a; }
}

// ================= fused attention split: scores + softmax (LDS) + PV partial
// grid (SP, H_, B_), block 256. chunk <= 64.  (unchanged from R4)
#define SCS 10
__global__ __launch_bounds__(256, 7) void attn_fused(
    const float* __restrict__ Q,
    const float* __restrict__ Kc, const float* __restrict__ Kn,
    const float* __restrict__ Vc, const float* __restrict__ Vn,
    const float* __restrict__ mask,
    float* __restrict__ Opart, float* __restrict__ ML,
    int TK, int TPp, int chunk)
{
  __shared__ float sc[64*SCS];      // scores then exp-weights, [jl][SCS]  (2.5KB)
  __shared__ float qs[8*64];        // q rows for this (b,*,h)             (2KB)
  __shared__ float kr[64*68];       // K tile [row][68] (phase 0/1) == red (phase 3) (17KB)
  const int tid = threadIdx.x;
  const int sp = blockIdx.x, h = blockIdx.y, b = blockIdx.z;
  const int SP = gridDim.x;
  const int j0 = sp * chunk;
  const int cnt = min(chunk, TK - j0);
  const int bh = b*H_ + h;

  // stage q: 512 floats (coalesced, lane=d)
  {
    const int i = tid >> 6, d = tid & 63;
    qs[tid]       = Q[((size_t)(b*TQ_ + i    ))*D_ + h*DH_ + d];
    qs[tid + 256] = Q[((size_t)(b*TQ_ + i + 4))*D_ + h*DH_ + d];
  }
  // stage K tile: cnt rows x 64 dims, coalesced float4 (16 lanes per row)
  for (int u = tid; u < cnt*16; u += 256) {
    const int r = u >> 4, c = u & 15;
    const int j = j0 + r;
    const float* kg = (j < TPp)
      ? Kc + ((size_t)b*TPp + j)*D_ + h*DH_
      : Kn + ((size_t)(b*TQ_ + (j - TPp)))*D_ + h*DH_;
    *(float4*)&kr[r*68 + c*4] = *(const float4*)(kg + c*4);
  }
  __syncthreads();

  // ---- phase 1: scores; 4 threads per key row (16 dims each), shfl_xor combine ----
  {
    const int jl = tid >> 2, qt = tid & 3;
    if (jl < cnt) {
      const float* krow = &kr[jl*68 + qt*16];
      const float4 k0 = *(const float4*)(krow);
      const float4 k1 = *(const float4*)(krow + 4);
      const float4 k2 = *(const float4*)(krow + 8);
      const float4 k3 = *(const float4*)(krow + 12);
      float acc[8];
#pragma unroll
      for (int i = 0; i < 8; ++i) {
        const float* qp = &qs[i*64 + qt*16];
        const float4 q0 = *(const float4*)(qp);
        const float4 q1 = *(const float4*)(qp + 4);
        const float4 q2 = *(const float4*)(qp + 8);
        const float4 q3 = *(const float4*)(qp + 12);
        acc[i] = q0.x*k0.x + q0.y*k0.y + q0.z*k0.z + q0.w*k0.w
               + q1.x*k1.x + q1.y*k1.y + q1.z*k1.z + q1.w*k1.w
               + q2.x*k2.x + q2.y*k2.y + q2.z*k2.z + q2.w*k2.w
               + q3.x*k3.x + q3.y*k3.y + q3.z*k3.z + q3.w*k3.w;
      }
#pragma unroll
      for (int i = 0; i < 8; ++i) {
        acc[i] += __shfl_xor(acc[i], 1, 64);
        acc[i] += __shfl_xor(acc[i], 2, 64);
      }
      if (qt == 0) {
        const int j = j0 + jl;
#pragma unroll
        for (int i = 0; i < 8; ++i) {
          float vv = acc[i]*0.125f;       // (dh^-0.25)^2 on the q.k product
          if (mask) vv += mask[(size_t)i*TK + j];
          sc[jl*SCS + i] = vv;
        }
      }
    }
  }
  __syncthreads();

  // ---- phase 2: per-split softmax, exp in place; 8 row-groups x 32 lanes ----
  {
    const int g = tid >> 5, l = tid & 31;
    float mx = -3.0e38f;
    for (int jl = l; jl < cnt; jl += 32) mx = fmaxf(mx, sc[jl*SCS + g]);
#pragma unroll
    for (int o = 16; o; o >>= 1) mx = fmaxf(mx, __shfl_down(mx, o, 32));
    mx = __shfl(mx, 0, 32);
    float sum = 0.f;
    for (int jl = l; jl < cnt; jl += 32) {
      const float e = __expf(sc[jl*SCS + g] - mx);
      sc[jl*SCS + g] = e;
      sum += e;
    }
#pragma unroll
    for (int o = 16; o; o >>= 1) sum += __shfl_down(sum, o, 32);
    if (l == 0) {
      ML[((size_t)bh*SP + sp)*16 + g]     = mx;
      ML[((size_t)bh*SP + sp)*16 + 8 + g] = sum;
    }
  }
  __syncthreads();

  // ---- phase 3: PV. Waves interleave over j (V read ONCE per block, 256B/instr);
  //      lane = d; all 8 q-rows accumulated per lane; LDS-broadcast weights ----
  {
    const int wv = tid >> 6;
    const int d  = tid & 63;
    float acc[8] = {0.f,0.f,0.f,0.f,0.f,0.f,0.f,0.f};
#pragma unroll 4
    for (int jl = wv; jl < cnt; jl += 4) {
      const int j = j0 + jl;
      const float vv = (j < TPp)
        ? Vc[((size_t)b*TPp + j)*D_ + h*DH_ + d]
        : Vn[((size_t)(b*TQ_ + (j - TPp)))*D_ + h*DH_ + d];
      const float2 p0 = *(const float2*)&sc[jl*SCS + 0];   // broadcast, conflict-free
      const float2 p1 = *(const float2*)&sc[jl*SCS + 2];
      const float2 p2 = *(const float2*)&sc[jl*SCS + 4];
      const float2 p3 = *(const float2*)&sc[jl*SCS + 6];
      acc[0] += p0.x*vv; acc[1] += p0.y*vv;
      acc[2] += p1.x*vv; acc[3] += p1.y*vv;
      acc[4] += p2.x*vv; acc[5] += p2.y*vv;
      acc[6] += p3.x*vv; acc[7] += p3.y*vv;
    }
#pragma unroll
    for (int i = 0; i < 8; ++i) kr[(wv*8 + i)*64 + d] = acc[i];
  }
  __syncthreads();
  {
#pragma unroll
    for (int t = 0; t < 2; ++t) {
      const int o = tid + t*256;        // < 512
      const int i = o >> 6, d = o & 63;
      const float r = kr[(0*8 + i)*64 + d] + kr[(1*8 + i)*64 + d]
                    + kr[(2*8 + i)*64 + d] + kr[(3*8 + i)*64 + d];
      Opart[(((size_t)bh*SP + sp)*8 + i)*64 + d] = r;
    }
  }
}

// ================= merge PV partials with split-softmax weights; ROW-major out (coalesced)
__global__ __launch_bounds__(256) void attn_pv_combine(
    const float* __restrict__ Opart, const float* __restrict__ ML,
    float* __restrict__ out, int SP)
{
  const int tid = threadIdx.x;
  const int h = blockIdx.x, b = blockIdx.y;
  const int bh = b*H_ + h;
  const int wv = tid >> 6, d = tid & 63;
  const int i0 = wv*2, i1 = i0 + 1;
  float M0 = -3.0e38f, M1 = -3.0e38f;
  for (int s = 0; s < SP; ++s) {
    M0 = fmaxf(M0, ML[((size_t)bh*SP + s)*16 + i0]);
    M1 = fmaxf(M1, ML[((size_t)bh*SP + s)*16 + i1]);
  }
  float L0 = 0.f, L1 = 0.f, o0 = 0.f, o1 = 0.f;
  for (int s = 0; s < SP; ++s) {
    const float w0 = __expf(ML[((size_t)bh*SP + s)*16 + i0] - M0);
    const float w1 = __expf(ML[((size_t)bh*SP + s)*16 + i1] - M1);
    L0 += w0 * ML[((size_t)bh*SP + s)*16 + 8 + i0];
    L1 += w1 * ML[((size_t)bh*SP + s)*16 + 8 + i1];
    o0 += w0 * Opart[(((size_t)bh*SP + s)*8 + i0)*64 + d];
    o1 += w1 * Opart[(((size_t)bh*SP + s)*8 + i1)*64 + d];
  }
  out[((size_t)(b*TQ_ + i0))*D_ + h*DH_ + d] = o0 / L0;
  out[((size_t)(b*TQ_ + i1))*D_ + h*DH_ + d] = o1 / L1;
}

extern "C" void kernel_launch(void* const* d_in, const int* in_sizes, int n_in,
                              void* d_out, int out_size, void* d_ws, size_t ws_size,
                              hipStream_t stream)
{
  (void)in_sizes; (void)n_in; (void)out_size; (void)ws_size;
  const float* x    = (const float*)d_in[0];
  const float* skc  = (const float*)d_in[1];
  const float* svc  = (const float*)d_in[2];
  const float* ck   = (const float*)d_in[3];
  const float* cv   = (const float*)d_in[4];
  const float* msk  = (const float*)d_in[5];
  const float* wq   = (const float*)d_in[6];
  const float* bq   = (const float*)d_in[7];
  const float* wk   = (const float*)d_in[8];
  const float* wvv  = (const float*)d_in[9];
  const float* bv   = (const float*)d_in[10];
  const float* wo   = (const float*)d_in[11];
  const float* bo   = (const float*)d_in[12];
  const float* cwq  = (const float*)d_in[13];
  const float* cbq  = (const float*)d_in[14];
  const float* cwo  = (const float*)d_in[15];
  const float* cbo  = (const float*)d_in[16];
  const float* ln1w = (const float*)d_in[17];
  const float* ln1b = (const float*)d_in[18];
  const float* ln2w = (const float*)d_in[19];
  const float* ln2b = (const float*)d_in[20];
  const float* ln3w = (const float*)d_in[21];
  const float* ln3b = (const float*)d_in[22];
  const float* w1   = (const float*)d_in[23];
  const float* b1   = (const float*)d_in[24];
  const float* w2   = (const float*)d_in[25];
  const float* b2   = (const float*)d_in[26];
  // d_in[27] = offset (int) — fixed at TP_ here.

  float* out_x  = (float*)d_out;
  float* out_k1 = out_x + 81920;
  float* out_v1 = out_x + 163840;

  float* ws = (float*)d_ws;
  float* xl   = ws + 0;               // [64][1280] row-major LN output, reused 3x
  float* qbuf = ws + 81920;           // q / qc row-major [64][1280]
  float* k1f  = ws + 163840;
  float* v1f  = ws + 245760;
  float* x2   = ws + 327680;
  float* x3   = ws + 409600;
  float* attO = ws + 491520;          // attn out row-major, reused 2x
  float* hbuf = ws + 573440;          // [64][5120] row-major
  float* Pg   = ws + 901120;          // split-K partials / attention Opart
  float* Pq   = Pg;
  float* Pk   = Pg + 819200;
  float* Pv   = Pg + 1638400;
  float* MLS  = ws + 4177920;         // 160*8*16
  float* MLC  = ws + 4218880;         // 160*24*16

  const dim3 blk(256);

  // --- self-attention ---
  ln_kernel<<<dim3(64), blk, 0, stream>>>(x, ln1w, ln1b, xl);
  gemm_splitk<<<dim3(10,10,3), blk, 0, stream>>>(xl, D_, wq, wk, wvv, Pq, Pk, Pv, 1280, 128);
  epilogue_qkv<<<dim3(320,1,3), blk, 0, stream>>>(Pq, Pk, Pv, bq, bv, qbuf, k1f, v1f, out_k1, out_v1);
  // SP=8, chunk=57 (8*57=456 >= 455)
  attn_fused<<<dim3(8,20,8), blk, 0, stream>>>(qbuf, skc, k1f, svc, v1f, msk, Pg, MLS, 455, 447, 57);
  attn_pv_combine<<<dim3(20,8), blk, 0, stream>>>(Pg, MLS, attO, 8);
  gemm_splitk<<<dim3(10,20,1), blk, 0, stream>>>(attO, D_, wo, wo, wo, Pq, Pq, Pq, 1280, 64);
  epilogue_ln<20><<<dim3(64), blk, 0, stream>>>(Pq, bo, x, ln2w, ln2b, x2, xl);

  // --- cross-attention ---
  gemm_splitk<<<dim3(10,20,1), blk, 0, stream>>>(xl, D_, cwq, cwq, cwq, Pq, Pq, Pq, 1280, 64);
  epilogue_kernel<20><<<dim3(320), blk, 0, stream>>>(Pq, 1280, cbq, nullptr, 0, qbuf, nullptr);
  // SP=24, chunk=64 (23*64=1472, last split 28 rows)
  attn_fused<<<dim3(24,20,8), blk, 0, stream>>>(qbuf, ck, nullptr, cv, nullptr, nullptr, Pg, MLC, 1500, 1500, 64);
  attn_pv_combine<<<dim3(20,8), blk, 0, stream>>>(Pg, MLC, attO, 24);
  gemm_splitk<<<dim3(10,20,1), blk, 0, stream>>>(attO, D_, cwo, cwo, cwo, Pq, Pq, Pq, 1280, 64);
  epilogue_ln<20><<<dim3(64), blk, 0, stream>>>(Pq, cbo, x2, ln3w, ln3b, x3, xl);

  // --- MLP ---
  gemm_splitk<<<dim3(40,10,1), blk, 0, stream>>>(xl, D_, w1, w1, w1, Pg, Pg, Pg, 5120, 128);
  epilogue_kernel<10><<<dim3(1280), blk, 0, stream>>>(Pg, 5120, b1, nullptr, 1, hbuf, nullptr);
  gemm_splitk<<<dim3(10,40,1), blk, 0, stream>>>(hbuf, DFF_, w2, w2, w2, Pg, Pg, Pg, 1280, 128);
  epilogue_kernel<40><<<dim3(320), blk, 0, stream>>>(Pg, 1280, b2, x3, 0, out_x, nullptr);
}